// Round 3
// baseline (213.004 us; speedup 1.0000x reference)
//
#include <hip/hip_runtime.h>
#include <math.h>

// Problem constants (from reference setup_inputs)
constexpr int NB = 16;          // batches
constexpr int XY = 512 * 512;   // pixels per image
constexpr int NV = XY / 4;      // float4 vectors per image
constexpr int GRIDX = 64;       // x-blocks per batch (4 blocks/CU resident)
constexpr int BLK = 256;
constexpr int NITER = NV / (GRIDX * BLK);   // = 4, compile-time trip count
constexpr int WS_STRIDE = 32;   // doubles per batch in workspace

// Workspace layout per batch (doubles), offset b*WS_STRIDE:
//  [0]      : mask count (Σ mask)
//  [1..4]   : S0[k]      = Σ w_k            (w_k = pred_k * mask)
//  [5..16]  : S1[k*3+m]  = Σ w_k * inp_m
//  [17..28] : S2[k*3+m]  = Σ w_k * inp_m^2
//  [29]     : Σ loglik * mask

__device__ __forceinline__ float waveReduce64(float v) {
#pragma unroll
    for (int off = 32; off > 0; off >>= 1) v += __shfl_down(v, off, 64);
    return v;
}

// Per-pixel moment accumulation on named scalar accumulators.
#define PIX1(h_, e0_, e1_, e2_, p0_, p1_, p2_, p3_) do {                      \
    float mm_ = ((h_) == 1) ? 1.f : 0.f;                                      \
    cnt += mm_;                                                               \
    float w0_ = (p0_) * mm_, w1_ = (p1_) * mm_, w2_ = (p2_) * mm_,            \
          w3_ = (p3_) * mm_;                                                  \
    s0_0 += w0_; s0_1 += w1_; s0_2 += w2_; s0_3 += w3_;                       \
    float t_;                                                                 \
    t_ = w0_ * (e0_); u00 += t_; q00 = fmaf(t_, (e0_), q00);                  \
    t_ = w0_ * (e1_); u01 += t_; q01 = fmaf(t_, (e1_), q01);                  \
    t_ = w0_ * (e2_); u02 += t_; q02 = fmaf(t_, (e2_), q02);                  \
    t_ = w1_ * (e0_); u10 += t_; q10 = fmaf(t_, (e0_), q10);                  \
    t_ = w1_ * (e1_); u11 += t_; q11 = fmaf(t_, (e1_), q11);                  \
    t_ = w1_ * (e2_); u12 += t_; q12 = fmaf(t_, (e2_), q12);                  \
    t_ = w2_ * (e0_); u20 += t_; q20 = fmaf(t_, (e0_), q20);                  \
    t_ = w2_ * (e1_); u21 += t_; q21 = fmaf(t_, (e1_), q21);                  \
    t_ = w2_ * (e2_); u22 += t_; q22 = fmaf(t_, (e2_), q22);                  \
    t_ = w3_ * (e0_); u30 += t_; q30 = fmaf(t_, (e0_), q30);                  \
    t_ = w3_ * (e1_); u31 += t_; q31 = fmaf(t_, (e1_), q31);                  \
    t_ = w3_ * (e2_); u32 += t_; q32 = fmaf(t_, (e2_), q32);                  \
} while (0)

#define RED(i_, var_) { float r_ = waveReduce64(var_); if (lane == 0) sh[wav][i_] = r_; }

// waves_per_eu(4,4): VGPR budget 512/4 = 128. The default heuristic targeted
// 8 waves/EU (VGPR=44) which left no registers for in-flight loads -> staged
// s_waitcnt inside every iteration, 50us even L3-warm. Grid is 4 blocks/CU
// = 16 waves/CU either way, so this costs no occupancy.
__global__ __attribute__((amdgpu_flat_work_group_size(256, 256),
                          amdgpu_waves_per_eu(4, 4)))
void pass1_moments(
        const float* __restrict__ predictions,
        const float* __restrict__ inputs,
        const int*   __restrict__ heart,
        double*      __restrict__ ws) {
    const int b = blockIdx.y;
    const float4* P1 = reinterpret_cast<const float4*>(predictions + (size_t)b * 5 * XY + 1 * XY);
    const float4* P2 = reinterpret_cast<const float4*>(predictions + (size_t)b * 5 * XY + 2 * XY);
    const float4* P3 = reinterpret_cast<const float4*>(predictions + (size_t)b * 5 * XY + 3 * XY);
    const float4* P4 = reinterpret_cast<const float4*>(predictions + (size_t)b * 5 * XY + 4 * XY);
    const float4* I0 = reinterpret_cast<const float4*>(inputs + (size_t)b * 3 * XY + 0 * XY);
    const float4* I1 = reinterpret_cast<const float4*>(inputs + (size_t)b * 3 * XY + 1 * XY);
    const float4* I2 = reinterpret_cast<const float4*>(inputs + (size_t)b * 3 * XY + 2 * XY);
    const int4*   H  = reinterpret_cast<const int4*>(heart + (size_t)b * XY);

    float cnt = 0.f;
    float s0_0 = 0.f, s0_1 = 0.f, s0_2 = 0.f, s0_3 = 0.f;
    float u00 = 0.f, u01 = 0.f, u02 = 0.f, u10 = 0.f, u11 = 0.f, u12 = 0.f;
    float u20 = 0.f, u21 = 0.f, u22 = 0.f, u30 = 0.f, u31 = 0.f, u32 = 0.f;
    float q00 = 0.f, q01 = 0.f, q02 = 0.f, q10 = 0.f, q11 = 0.f, q12 = 0.f;
    float q20 = 0.f, q21 = 0.f, q22 = 0.f, q30 = 0.f, q31 = 0.f, q32 = 0.f;

    const int base = blockIdx.x * BLK + threadIdx.x;

    // Compile-time trip count; fully unrolled so the scheduler can hoist
    // loads across iterations within the 128-VGPR budget.
#pragma unroll
    for (int it = 0; it < NITER; ++it) {
        const int v = base + it * (GRIDX * BLK);
        int4   h  = H[v];
        float4 f0 = I0[v], f1 = I1[v], f2 = I2[v];
        float4 g0 = P1[v], g1 = P2[v], g2 = P3[v], g3 = P4[v];
        PIX1(h.x, f0.x, f1.x, f2.x, g0.x, g1.x, g2.x, g3.x);
        PIX1(h.y, f0.y, f1.y, f2.y, g0.y, g1.y, g2.y, g3.y);
        PIX1(h.z, f0.z, f1.z, f2.z, g0.z, g1.z, g2.z, g3.z);
        PIX1(h.w, f0.w, f1.w, f2.w, g0.w, g1.w, g2.w, g3.w);
    }

    __shared__ float sh[4][29];
    const int lane = threadIdx.x & 63;
    const int wav  = threadIdx.x >> 6;
    RED(0, cnt);
    RED(1, s0_0); RED(2, s0_1); RED(3, s0_2); RED(4, s0_3);
    RED(5, u00); RED(6, u01); RED(7, u02);
    RED(8, u10); RED(9, u11); RED(10, u12);
    RED(11, u20); RED(12, u21); RED(13, u22);
    RED(14, u30); RED(15, u31); RED(16, u32);
    RED(17, q00); RED(18, q01); RED(19, q02);
    RED(20, q10); RED(21, q11); RED(22, q12);
    RED(23, q20); RED(24, q21); RED(25, q22);
    RED(26, q30); RED(27, q31); RED(28, q32);
    __syncthreads();
    if (threadIdx.x < 29) {
        float v = sh[0][threadIdx.x] + sh[1][threadIdx.x] + sh[2][threadIdx.x] + sh[3][threadIdx.x];
        atomicAdd(&ws[(size_t)b * WS_STRIDE + threadIdx.x], (double)v);
    }
}

// Per-component parameter reconstruction (block-uniform, f64 for the ~4x
// cancellation in S2 - 2 mu S1 + mu^2 S0).
#define PARAMK(K_, mu0_, mu1_, mu2_, h0_, h1_, h2_, C_) {                     \
    double S0_ = w[1 + (K_)];                                                 \
    double den_ = S0_ + 1e-10;                                                \
    double Cd_ = 1.0;                                                         \
    double S1_, S2_, muv_, var_;                                              \
    S1_ = w[5 + (K_)*3 + 0]; S2_ = w[17 + (K_)*3 + 0];                        \
    muv_ = S1_ / den_;                                                        \
    var_ = (S2_ - 2.0 * muv_ * S1_ + muv_ * muv_ * S0_) / den_ + 1e-10;       \
    mu0_ = (float)muv_; h0_ = (float)(0.5 / var_);                            \
    Cd_ *= 1.0 / sqrt(6.283185307179586 * var_);                              \
    S1_ = w[5 + (K_)*3 + 1]; S2_ = w[17 + (K_)*3 + 1];                        \
    muv_ = S1_ / den_;                                                        \
    var_ = (S2_ - 2.0 * muv_ * S1_ + muv_ * muv_ * S0_) / den_ + 1e-10;       \
    mu1_ = (float)muv_; h1_ = (float)(0.5 / var_);                            \
    Cd_ *= 1.0 / sqrt(6.283185307179586 * var_);                              \
    S1_ = w[5 + (K_)*3 + 2]; S2_ = w[17 + (K_)*3 + 2];                        \
    muv_ = S1_ / den_;                                                        \
    var_ = (S2_ - 2.0 * muv_ * S1_ + muv_ * muv_ * S0_) / den_ + 1e-10;       \
    mu2_ = (float)muv_; h2_ = (float)(0.5 / var_);                            \
    Cd_ *= 1.0 / sqrt(6.283185307179586 * var_);                              \
    C_ = (float)Cd_;                                                          \
}

#define PIX2(h_, e0_, e1_, e2_, p0_, p1_, p2_, p3_) do {                      \
    float m_ = ((h_) == 1) ? 1.f : 0.f;                                       \
    float d0_, d1_, d2_, ex_, pc_;                                            \
    float mix_;                                                               \
    d0_ = (e0_) - mu00; d1_ = (e1_) - mu01; d2_ = (e2_) - mu02;               \
    ex_ = fmaf(d0_ * d0_, hv00, fmaf(d1_ * d1_, hv01, d2_ * d2_ * hv02));     \
    pc_ = (p0_) * (p0_) * (p0_);                                              \
    mix_ = C0 * pc_ * __expf(-ex_);                                           \
    d0_ = (e0_) - mu10; d1_ = (e1_) - mu11; d2_ = (e2_) - mu12;               \
    ex_ = fmaf(d0_ * d0_, hv10, fmaf(d1_ * d1_, hv11, d2_ * d2_ * hv12));     \
    pc_ = (p1_) * (p1_) * (p1_);                                              \
    mix_ = fmaf(C1 * pc_, __expf(-ex_), mix_);                                \
    d0_ = (e0_) - mu20; d1_ = (e1_) - mu21; d2_ = (e2_) - mu22;               \
    ex_ = fmaf(d0_ * d0_, hv20, fmaf(d1_ * d1_, hv21, d2_ * d2_ * hv22));     \
    pc_ = (p2_) * (p2_) * (p2_);                                              \
    mix_ = fmaf(C2 * pc_, __expf(-ex_), mix_);                                \
    d0_ = (e0_) - mu30; d1_ = (e1_) - mu31; d2_ = (e2_) - mu32;               \
    ex_ = fmaf(d0_ * d0_, hv30, fmaf(d1_ * d1_, hv31, d2_ * d2_ * hv32));     \
    pc_ = (p3_) * (p3_) * (p3_);                                              \
    mix_ = fmaf(C3 * pc_, __expf(-ex_), mix_);                                \
    lacc += m_ * __logf(mix_ + 1e-10f);                                       \
} while (0)

__global__ __attribute__((amdgpu_flat_work_group_size(256, 256),
                          amdgpu_waves_per_eu(4, 4)))
void pass2_loglik(
        const float* __restrict__ predictions,
        const float* __restrict__ inputs,
        const int*   __restrict__ heart,
        double*      __restrict__ ws) {
    const int b = blockIdx.y;
    const double* w = ws + (size_t)b * WS_STRIDE;

    float mu00, mu01, mu02, mu10, mu11, mu12, mu20, mu21, mu22, mu30, mu31, mu32;
    float hv00, hv01, hv02, hv10, hv11, hv12, hv20, hv21, hv22, hv30, hv31, hv32;
    float C0, C1, C2, C3;
    PARAMK(0, mu00, mu01, mu02, hv00, hv01, hv02, C0);
    PARAMK(1, mu10, mu11, mu12, hv10, hv11, hv12, C1);
    PARAMK(2, mu20, mu21, mu22, hv20, hv21, hv22, C2);
    PARAMK(3, mu30, mu31, mu32, hv30, hv31, hv32, C3);

    const float4* P1 = reinterpret_cast<const float4*>(predictions + (size_t)b * 5 * XY + 1 * XY);
    const float4* P2 = reinterpret_cast<const float4*>(predictions + (size_t)b * 5 * XY + 2 * XY);
    const float4* P3 = reinterpret_cast<const float4*>(predictions + (size_t)b * 5 * XY + 3 * XY);
    const float4* P4 = reinterpret_cast<const float4*>(predictions + (size_t)b * 5 * XY + 4 * XY);
    const float4* I0 = reinterpret_cast<const float4*>(inputs + (size_t)b * 3 * XY + 0 * XY);
    const float4* I1 = reinterpret_cast<const float4*>(inputs + (size_t)b * 3 * XY + 1 * XY);
    const float4* I2 = reinterpret_cast<const float4*>(inputs + (size_t)b * 3 * XY + 2 * XY);
    const int4*   H  = reinterpret_cast<const int4*>(heart + (size_t)b * XY);

    float lacc = 0.f;
    const int base = blockIdx.x * BLK + threadIdx.x;

#pragma unroll
    for (int it = 0; it < NITER; ++it) {
        const int v = base + it * (GRIDX * BLK);
        int4   h  = H[v];
        float4 f0 = I0[v], f1 = I1[v], f2 = I2[v];
        float4 g0 = P1[v], g1 = P2[v], g2 = P3[v], g3 = P4[v];
        PIX2(h.x, f0.x, f1.x, f2.x, g0.x, g1.x, g2.x, g3.x);
        PIX2(h.y, f0.y, f1.y, f2.y, g0.y, g1.y, g2.y, g3.y);
        PIX2(h.z, f0.z, f1.z, f2.z, g0.z, g1.z, g2.z, g3.z);
        PIX2(h.w, f0.w, f1.w, f2.w, g0.w, g1.w, g2.w, g3.w);
    }

    __shared__ float sh[4];
    const int lane = threadIdx.x & 63;
    const int wav  = threadIdx.x >> 6;
    float v = waveReduce64(lacc);
    if (lane == 0) sh[wav] = v;
    __syncthreads();
    if (threadIdx.x == 0) {
        float t = sh[0] + sh[1] + sh[2] + sh[3];
        atomicAdd(&ws[(size_t)b * WS_STRIDE + 29], (double)t);
    }
}

__global__ void finalize_kernel(const double* __restrict__ ws, float* __restrict__ out) {
    const int lane = threadIdx.x;
    double v = 0.0;
    if (lane < NB) {
        double cntv = ws[(size_t)lane * WS_STRIDE + 0];
        double ll   = ws[(size_t)lane * WS_STRIDE + 29];
        v = -ll / cntv;
    }
#pragma unroll
    for (int off = 8; off > 0; off >>= 1) v += __shfl_down(v, off, 64);
    if (lane == 0) out[0] = (float)(v / (double)NB);
}

extern "C" void kernel_launch(void* const* d_in, const int* in_sizes, int n_in,
                              void* d_out, int out_size, void* d_ws, size_t ws_size,
                              hipStream_t stream) {
    const float* predictions = (const float*)d_in[0];
    const float* inputs      = (const float*)d_in[1];
    const int*   heart       = (const int*)d_in[2];
    float*  out = (float*)d_out;
    double* ws  = (double*)d_ws;

    // zero the accumulator workspace (harness poisons it with 0xAA)
    hipMemsetAsync(d_ws, 0, (size_t)NB * WS_STRIDE * sizeof(double), stream);

    pass1_moments<<<dim3(GRIDX, NB), BLK, 0, stream>>>(predictions, inputs, heart, ws);
    pass2_loglik <<<dim3(GRIDX, NB), BLK, 0, stream>>>(predictions, inputs, heart, ws);
    finalize_kernel<<<1, 64, 0, stream>>>(ws, out);
}

// Round 4
// 197.951 us; speedup vs baseline: 1.0760x; 1.0760x over previous
//
#include <hip/hip_runtime.h>
#include <math.h>

// Problem constants (from reference setup_inputs)
constexpr int NB = 16;          // batches
constexpr int XY = 512 * 512;   // pixels per image
constexpr int NV = XY / 4;      // float4 vectors per image
constexpr int GRIDX = 128;      // x-blocks per batch -> 2048 blocks = 8/CU = 32 waves/CU
constexpr int BLK = 256;
constexpr int WS_STRIDE = 32;   // doubles per batch in workspace

// Workspace layout per batch (doubles), offset b*WS_STRIDE:
//  [0]      : mask count (Σ mask)
//  [1..4]   : S0[k]      = Σ w_k            (w_k = pred_k * mask)
//  [5..16]  : S1[k*3+m]  = Σ w_k * inp_m
//  [17..28] : S2[k*3+m]  = Σ w_k * inp_m^2
//  [29]     : Σ loglik * mask
//
// Round-3 lesson: waves_per_eu(4,4)+full unroll -> VGPR=64 + 23MB scratch
// spill, 70us. Round-2 shape (VGPR=44, no spill) at only 4 blocks/CU was
// latency-bound at 16/32 waves/CU. Fix = same code, 8 blocks/CU.

__device__ __forceinline__ float waveReduce64(float v) {
#pragma unroll
    for (int off = 32; off > 0; off >>= 1) v += __shfl_down(v, off, 64);
    return v;
}

#define PIX1(h_, e0_, e1_, e2_, p0_, p1_, p2_, p3_) do {                      \
    float mm_ = ((h_) == 1) ? 1.f : 0.f;                                      \
    cnt += mm_;                                                               \
    float w0_ = (p0_) * mm_, w1_ = (p1_) * mm_, w2_ = (p2_) * mm_,            \
          w3_ = (p3_) * mm_;                                                  \
    s0_0 += w0_; s0_1 += w1_; s0_2 += w2_; s0_3 += w3_;                       \
    float t_;                                                                 \
    t_ = w0_ * (e0_); u00 += t_; q00 = fmaf(t_, (e0_), q00);                  \
    t_ = w0_ * (e1_); u01 += t_; q01 = fmaf(t_, (e1_), q01);                  \
    t_ = w0_ * (e2_); u02 += t_; q02 = fmaf(t_, (e2_), q02);                  \
    t_ = w1_ * (e0_); u10 += t_; q10 = fmaf(t_, (e0_), q10);                  \
    t_ = w1_ * (e1_); u11 += t_; q11 = fmaf(t_, (e1_), q11);                  \
    t_ = w1_ * (e2_); u12 += t_; q12 = fmaf(t_, (e2_), q12);                  \
    t_ = w2_ * (e0_); u20 += t_; q20 = fmaf(t_, (e0_), q20);                  \
    t_ = w2_ * (e1_); u21 += t_; q21 = fmaf(t_, (e1_), q21);                  \
    t_ = w2_ * (e2_); u22 += t_; q22 = fmaf(t_, (e2_), q22);                  \
    t_ = w3_ * (e0_); u30 += t_; q30 = fmaf(t_, (e0_), q30);                  \
    t_ = w3_ * (e1_); u31 += t_; q31 = fmaf(t_, (e1_), q31);                  \
    t_ = w3_ * (e2_); u32 += t_; q32 = fmaf(t_, (e2_), q32);                  \
} while (0)

#define RED(i_, var_) { float r_ = waveReduce64(var_); if (lane == 0) sh[wav][i_] = r_; }

__global__ __launch_bounds__(256) void pass1_moments(
        const float* __restrict__ predictions,
        const float* __restrict__ inputs,
        const int*   __restrict__ heart,
        double*      __restrict__ ws) {
    const int b = blockIdx.y;
    const float4* P1 = reinterpret_cast<const float4*>(predictions + (size_t)b * 5 * XY + 1 * XY);
    const float4* P2 = reinterpret_cast<const float4*>(predictions + (size_t)b * 5 * XY + 2 * XY);
    const float4* P3 = reinterpret_cast<const float4*>(predictions + (size_t)b * 5 * XY + 3 * XY);
    const float4* P4 = reinterpret_cast<const float4*>(predictions + (size_t)b * 5 * XY + 4 * XY);
    const float4* I0 = reinterpret_cast<const float4*>(inputs + (size_t)b * 3 * XY + 0 * XY);
    const float4* I1 = reinterpret_cast<const float4*>(inputs + (size_t)b * 3 * XY + 1 * XY);
    const float4* I2 = reinterpret_cast<const float4*>(inputs + (size_t)b * 3 * XY + 2 * XY);
    const int4*   H  = reinterpret_cast<const int4*>(heart + (size_t)b * XY);

    float cnt = 0.f;
    float s0_0 = 0.f, s0_1 = 0.f, s0_2 = 0.f, s0_3 = 0.f;
    float u00 = 0.f, u01 = 0.f, u02 = 0.f, u10 = 0.f, u11 = 0.f, u12 = 0.f;
    float u20 = 0.f, u21 = 0.f, u22 = 0.f, u30 = 0.f, u31 = 0.f, u32 = 0.f;
    float q00 = 0.f, q01 = 0.f, q02 = 0.f, q10 = 0.f, q11 = 0.f, q12 = 0.f;
    float q20 = 0.f, q21 = 0.f, q22 = 0.f, q30 = 0.f, q31 = 0.f, q32 = 0.f;

    const int tid0   = blockIdx.x * BLK + threadIdx.x;
    const int stride = GRIDX * BLK;

    for (int v = tid0; v < NV; v += stride) {
        int4   h  = H[v];
        float4 f0 = I0[v], f1 = I1[v], f2 = I2[v];
        float4 g0 = P1[v], g1 = P2[v], g2 = P3[v], g3 = P4[v];
        PIX1(h.x, f0.x, f1.x, f2.x, g0.x, g1.x, g2.x, g3.x);
        PIX1(h.y, f0.y, f1.y, f2.y, g0.y, g1.y, g2.y, g3.y);
        PIX1(h.z, f0.z, f1.z, f2.z, g0.z, g1.z, g2.z, g3.z);
        PIX1(h.w, f0.w, f1.w, f2.w, g0.w, g1.w, g2.w, g3.w);
    }

    __shared__ float sh[4][29];
    const int lane = threadIdx.x & 63;
    const int wav  = threadIdx.x >> 6;
    RED(0, cnt);
    RED(1, s0_0); RED(2, s0_1); RED(3, s0_2); RED(4, s0_3);
    RED(5, u00); RED(6, u01); RED(7, u02);
    RED(8, u10); RED(9, u11); RED(10, u12);
    RED(11, u20); RED(12, u21); RED(13, u22);
    RED(14, u30); RED(15, u31); RED(16, u32);
    RED(17, q00); RED(18, q01); RED(19, q02);
    RED(20, q10); RED(21, q11); RED(22, q12);
    RED(23, q20); RED(24, q21); RED(25, q22);
    RED(26, q30); RED(27, q31); RED(28, q32);
    __syncthreads();
    if (threadIdx.x < 29) {
        float v = sh[0][threadIdx.x] + sh[1][threadIdx.x] + sh[2][threadIdx.x] + sh[3][threadIdx.x];
        atomicAdd(&ws[(size_t)b * WS_STRIDE + threadIdx.x], (double)v);
    }
}

#define PARAMK(K_, mu0_, mu1_, mu2_, h0_, h1_, h2_, C_) {                     \
    double S0_ = w[1 + (K_)];                                                 \
    double den_ = S0_ + 1e-10;                                                \
    double Cd_ = 1.0;                                                         \
    double S1_, S2_, muv_, var_;                                              \
    S1_ = w[5 + (K_)*3 + 0]; S2_ = w[17 + (K_)*3 + 0];                        \
    muv_ = S1_ / den_;                                                        \
    var_ = (S2_ - 2.0 * muv_ * S1_ + muv_ * muv_ * S0_) / den_ + 1e-10;       \
    mu0_ = (float)muv_; h0_ = (float)(0.5 / var_);                            \
    Cd_ *= 1.0 / sqrt(6.283185307179586 * var_);                              \
    S1_ = w[5 + (K_)*3 + 1]; S2_ = w[17 + (K_)*3 + 1];                        \
    muv_ = S1_ / den_;                                                        \
    var_ = (S2_ - 2.0 * muv_ * S1_ + muv_ * muv_ * S0_) / den_ + 1e-10;       \
    mu1_ = (float)muv_; h1_ = (float)(0.5 / var_);                            \
    Cd_ *= 1.0 / sqrt(6.283185307179586 * var_);                              \
    S1_ = w[5 + (K_)*3 + 2]; S2_ = w[17 + (K_)*3 + 2];                        \
    muv_ = S1_ / den_;                                                        \
    var_ = (S2_ - 2.0 * muv_ * S1_ + muv_ * muv_ * S0_) / den_ + 1e-10;       \
    mu2_ = (float)muv_; h2_ = (float)(0.5 / var_);                            \
    Cd_ *= 1.0 / sqrt(6.283185307179586 * var_);                              \
    C_ = (float)Cd_;                                                          \
}

#define PIX2(h_, e0_, e1_, e2_, p0_, p1_, p2_, p3_) do {                      \
    float m_ = ((h_) == 1) ? 1.f : 0.f;                                       \
    float d0_, d1_, d2_, ex_, pc_;                                            \
    float mix_;                                                               \
    d0_ = (e0_) - mu00; d1_ = (e1_) - mu01; d2_ = (e2_) - mu02;               \
    ex_ = fmaf(d0_ * d0_, hv00, fmaf(d1_ * d1_, hv01, d2_ * d2_ * hv02));     \
    pc_ = (p0_) * (p0_) * (p0_);                                              \
    mix_ = C0 * pc_ * __expf(-ex_);                                           \
    d0_ = (e0_) - mu10; d1_ = (e1_) - mu11; d2_ = (e2_) - mu12;               \
    ex_ = fmaf(d0_ * d0_, hv10, fmaf(d1_ * d1_, hv11, d2_ * d2_ * hv12));     \
    pc_ = (p1_) * (p1_) * (p1_);                                              \
    mix_ = fmaf(C1 * pc_, __expf(-ex_), mix_);                                \
    d0_ = (e0_) - mu20; d1_ = (e1_) - mu21; d2_ = (e2_) - mu22;               \
    ex_ = fmaf(d0_ * d0_, hv20, fmaf(d1_ * d1_, hv21, d2_ * d2_ * hv22));     \
    pc_ = (p2_) * (p2_) * (p2_);                                              \
    mix_ = fmaf(C2 * pc_, __expf(-ex_), mix_);                                \
    d0_ = (e0_) - mu30; d1_ = (e1_) - mu31; d2_ = (e2_) - mu32;               \
    ex_ = fmaf(d0_ * d0_, hv30, fmaf(d1_ * d1_, hv31, d2_ * d2_ * hv32));     \
    pc_ = (p3_) * (p3_) * (p3_);                                              \
    mix_ = fmaf(C3 * pc_, __expf(-ex_), mix_);                                \
    lacc += m_ * __logf(mix_ + 1e-10f);                                       \
} while (0)

__global__ __launch_bounds__(256) void pass2_loglik(
        const float* __restrict__ predictions,
        const float* __restrict__ inputs,
        const int*   __restrict__ heart,
        double*      __restrict__ ws) {
    const int b = blockIdx.y;
    const double* w = ws + (size_t)b * WS_STRIDE;

    float mu00, mu01, mu02, mu10, mu11, mu12, mu20, mu21, mu22, mu30, mu31, mu32;
    float hv00, hv01, hv02, hv10, hv11, hv12, hv20, hv21, hv22, hv30, hv31, hv32;
    float C0, C1, C2, C3;
    PARAMK(0, mu00, mu01, mu02, hv00, hv01, hv02, C0);
    PARAMK(1, mu10, mu11, mu12, hv10, hv11, hv12, C1);
    PARAMK(2, mu20, mu21, mu22, hv20, hv21, hv22, C2);
    PARAMK(3, mu30, mu31, mu32, hv30, hv31, hv32, C3);

    const float4* P1 = reinterpret_cast<const float4*>(predictions + (size_t)b * 5 * XY + 1 * XY);
    const float4* P2 = reinterpret_cast<const float4*>(predictions + (size_t)b * 5 * XY + 2 * XY);
    const float4* P3 = reinterpret_cast<const float4*>(predictions + (size_t)b * 5 * XY + 3 * XY);
    const float4* P4 = reinterpret_cast<const float4*>(predictions + (size_t)b * 5 * XY + 4 * XY);
    const float4* I0 = reinterpret_cast<const float4*>(inputs + (size_t)b * 3 * XY + 0 * XY);
    const float4* I1 = reinterpret_cast<const float4*>(inputs + (size_t)b * 3 * XY + 1 * XY);
    const float4* I2 = reinterpret_cast<const float4*>(inputs + (size_t)b * 3 * XY + 2 * XY);
    const int4*   H  = reinterpret_cast<const int4*>(heart + (size_t)b * XY);

    float lacc = 0.f;
    const int tid0   = blockIdx.x * BLK + threadIdx.x;
    const int stride = GRIDX * BLK;

    for (int v = tid0; v < NV; v += stride) {
        int4   h  = H[v];
        float4 f0 = I0[v], f1 = I1[v], f2 = I2[v];
        float4 g0 = P1[v], g1 = P2[v], g2 = P3[v], g3 = P4[v];
        PIX2(h.x, f0.x, f1.x, f2.x, g0.x, g1.x, g2.x, g3.x);
        PIX2(h.y, f0.y, f1.y, f2.y, g0.y, g1.y, g2.y, g3.y);
        PIX2(h.z, f0.z, f1.z, f2.z, g0.z, g1.z, g2.z, g3.z);
        PIX2(h.w, f0.w, f1.w, f2.w, g0.w, g1.w, g2.w, g3.w);
    }

    __shared__ float sh[4];
    const int lane = threadIdx.x & 63;
    const int wav  = threadIdx.x >> 6;
    float v = waveReduce64(lacc);
    if (lane == 0) sh[wav] = v;
    __syncthreads();
    if (threadIdx.x == 0) {
        float t = sh[0] + sh[1] + sh[2] + sh[3];
        atomicAdd(&ws[(size_t)b * WS_STRIDE + 29], (double)t);
    }
}

__global__ void finalize_kernel(const double* __restrict__ ws, float* __restrict__ out) {
    const int lane = threadIdx.x;
    double v = 0.0;
    if (lane < NB) {
        double cntv = ws[(size_t)lane * WS_STRIDE + 0];
        double ll   = ws[(size_t)lane * WS_STRIDE + 29];
        v = -ll / cntv;
    }
#pragma unroll
    for (int off = 8; off > 0; off >>= 1) v += __shfl_down(v, off, 64);
    if (lane == 0) out[0] = (float)(v / (double)NB);
}

extern "C" void kernel_launch(void* const* d_in, const int* in_sizes, int n_in,
                              void* d_out, int out_size, void* d_ws, size_t ws_size,
                              hipStream_t stream) {
    const float* predictions = (const float*)d_in[0];
    const float* inputs      = (const float*)d_in[1];
    const int*   heart       = (const int*)d_in[2];
    float*  out = (float*)d_out;
    double* ws  = (double*)d_ws;

    // zero the accumulator workspace (harness poisons it with 0xAA)
    hipMemsetAsync(d_ws, 0, (size_t)NB * WS_STRIDE * sizeof(double), stream);

    pass1_moments<<<dim3(GRIDX, NB), BLK, 0, stream>>>(predictions, inputs, heart, ws);
    pass2_loglik <<<dim3(GRIDX, NB), BLK, 0, stream>>>(predictions, inputs, heart, ws);
    finalize_kernel<<<1, 64, 0, stream>>>(ws, out);
}

// Round 5
// 196.302 us; speedup vs baseline: 1.0851x; 1.0084x over previous
//
#include <hip/hip_runtime.h>
#include <math.h>

// Problem constants (from reference setup_inputs)
constexpr int NB = 16;          // batches
constexpr int XY = 512 * 512;   // pixels per image
constexpr int NV = XY / 4;      // float4 vectors per image
constexpr int BLK = 256;
constexpr int GRIDX = 64;       // blocks per batch -> 1024 blocks = 4/CU
constexpr int TILE_V = 256;     // float4-vectors per tile (= 1024 pixels, 4 KB/channel)
constexpr int TILES_PER_BATCH = NV / TILE_V;        // 256
constexpr int TPB = TILES_PER_BATCH / GRIDX;        // 4 tiles per block
constexpr int WS_STRIDE = 32;   // doubles per batch in workspace

// Workspace layout per batch (doubles), offset b*WS_STRIDE:
//  [0]      : mask count (Σ mask)
//  [1..4]   : S0[k]      = Σ w_k            (w_k = pred_k * mask)
//  [5..16]  : S1[k*3+m]  = Σ w_k * inp_m
//  [17..28] : S2[k*3+m]  = Σ w_k * inp_m^2
//  [29]     : Σ loglik * mask
//
// R1-R4 lesson: per-thread 8-stream float4 loads are stuck at ~50us
// regardless of grid size / unroll / VGPR knobs (VALUBusy 14%, HBM 16%,
// L3-warm replay equally slow). At VGPR=44 the 8 load destinations can't
// stay in flight -> staged waitcnt serialization per wave. Fix: stage
// tiles via global_load_lds (no VGPR dest, 32KB in flight per block).

__device__ __forceinline__ float waveReduce64(float v) {
#pragma unroll
    for (int off = 32; off > 0; off >>= 1) v += __shfl_down(v, off, 64);
    return v;
}

#if __has_builtin(__builtin_amdgcn_global_load_lds)
#define HAVE_GLL 1
__device__ __forceinline__ void g2lds16(const void* g, void* l) {
    __builtin_amdgcn_global_load_lds(
        (const __attribute__((address_space(1))) void*)g,
        (__attribute__((address_space(3))) void*)l, 16, 0, 0);
}
#else
#define HAVE_GLL 0
#endif

#define PIX1(h_, e0_, e1_, e2_, p0_, p1_, p2_, p3_) do {                      \
    float mm_ = ((h_) == 1) ? 1.f : 0.f;                                      \
    cnt += mm_;                                                               \
    float w0_ = (p0_) * mm_, w1_ = (p1_) * mm_, w2_ = (p2_) * mm_,            \
          w3_ = (p3_) * mm_;                                                  \
    s0_0 += w0_; s0_1 += w1_; s0_2 += w2_; s0_3 += w3_;                       \
    float t_;                                                                 \
    t_ = w0_ * (e0_); u00 += t_; q00 = fmaf(t_, (e0_), q00);                  \
    t_ = w0_ * (e1_); u01 += t_; q01 = fmaf(t_, (e1_), q01);                  \
    t_ = w0_ * (e2_); u02 += t_; q02 = fmaf(t_, (e2_), q02);                  \
    t_ = w1_ * (e0_); u10 += t_; q10 = fmaf(t_, (e0_), q10);                  \
    t_ = w1_ * (e1_); u11 += t_; q11 = fmaf(t_, (e1_), q11);                  \
    t_ = w1_ * (e2_); u12 += t_; q12 = fmaf(t_, (e2_), q12);                  \
    t_ = w2_ * (e0_); u20 += t_; q20 = fmaf(t_, (e0_), q20);                  \
    t_ = w2_ * (e1_); u21 += t_; q21 = fmaf(t_, (e1_), q21);                  \
    t_ = w2_ * (e2_); u22 += t_; q22 = fmaf(t_, (e2_), q22);                  \
    t_ = w3_ * (e0_); u30 += t_; q30 = fmaf(t_, (e0_), q30);                  \
    t_ = w3_ * (e1_); u31 += t_; q31 = fmaf(t_, (e1_), q31);                  \
    t_ = w3_ * (e2_); u32 += t_; q32 = fmaf(t_, (e2_), q32);                  \
} while (0)

#define RED(i_, var_) { float r_ = waveReduce64(var_); if (lane == 0) sh[wav][i_] = r_; }

// Stage one tile (8 channels x 4KB) into LDS. Channel bases come from the
// LDS pointer table cb[] (runtime wave-uniform index -> LDS read, no scratch).
#define STAGE_TILE(tile_)                                                     \
    {                                                                         \
        const int vbase_ = (tile_) * TILE_V;                                  \
        _Pragma("unroll")                                                     \
        for (int jj_ = 0; jj_ < 8; ++jj_) {                                   \
            int j_ = wav * 8 + jj_;                                           \
            int ch_ = j_ >> 2, chunk_ = j_ & 3;                               \
            const float4* gp_ = cb[ch_] + (vbase_ + chunk_ * 64 + lane);      \
            STAGE_ONE(gp_, ch_, chunk_);                                      \
        }                                                                     \
    }

#if HAVE_GLL
#define STAGE_ONE(gp_, ch_, chunk_) g2lds16((const void*)(gp_), (void*)&tileBuf[ch_][(chunk_) * 64])
#else
#define STAGE_ONE(gp_, ch_, chunk_) tileBuf[ch_][(chunk_) * 64 + lane] = *(gp_)
#endif

__global__ __launch_bounds__(256) void pass1_moments(
        const float* __restrict__ predictions,
        const float* __restrict__ inputs,
        const int*   __restrict__ heart,
        double*      __restrict__ ws) {
    const int b = blockIdx.y;

    __shared__ float4 tileBuf[8][TILE_V];      // 32 KB
    __shared__ const float4* cb[8];
    __shared__ float sh[4][29];

    const int tx   = threadIdx.x;
    const int lane = tx & 63;
    const int wav  = tx >> 6;

    if (tx < 8) {
        const float* p;
        if (tx == 0)      p = (const float*)(heart + (size_t)b * XY);
        else if (tx <= 3) p = inputs + (size_t)b * 3 * XY + (size_t)(tx - 1) * XY;
        else              p = predictions + (size_t)b * 5 * XY + (size_t)(tx - 3) * XY;
        cb[tx] = reinterpret_cast<const float4*>(p);
    }
    __syncthreads();

    float cnt = 0.f;
    float s0_0 = 0.f, s0_1 = 0.f, s0_2 = 0.f, s0_3 = 0.f;
    float u00 = 0.f, u01 = 0.f, u02 = 0.f, u10 = 0.f, u11 = 0.f, u12 = 0.f;
    float u20 = 0.f, u21 = 0.f, u22 = 0.f, u30 = 0.f, u31 = 0.f, u32 = 0.f;
    float q00 = 0.f, q01 = 0.f, q02 = 0.f, q10 = 0.f, q11 = 0.f, q12 = 0.f;
    float q20 = 0.f, q21 = 0.f, q22 = 0.f, q30 = 0.f, q31 = 0.f, q32 = 0.f;

    const int tile0 = blockIdx.x * TPB;
    for (int t = 0; t < TPB; ++t) {
        STAGE_TILE(tile0 + t);
        __syncthreads();   // drains vmcnt(0): LDS tile complete
        int4   h  = ((const int4*)tileBuf[0])[tx];
        float4 f0 = tileBuf[1][tx], f1 = tileBuf[2][tx], f2 = tileBuf[3][tx];
        float4 g0 = tileBuf[4][tx], g1 = tileBuf[5][tx], g2 = tileBuf[6][tx], g3 = tileBuf[7][tx];
        PIX1(h.x, f0.x, f1.x, f2.x, g0.x, g1.x, g2.x, g3.x);
        PIX1(h.y, f0.y, f1.y, f2.y, g0.y, g1.y, g2.y, g3.y);
        PIX1(h.z, f0.z, f1.z, f2.z, g0.z, g1.z, g2.z, g3.z);
        PIX1(h.w, f0.w, f1.w, f2.w, g0.w, g1.w, g2.w, g3.w);
        __syncthreads();   // protect tile before next stage overwrites
    }

    RED(0, cnt);
    RED(1, s0_0); RED(2, s0_1); RED(3, s0_2); RED(4, s0_3);
    RED(5, u00); RED(6, u01); RED(7, u02);
    RED(8, u10); RED(9, u11); RED(10, u12);
    RED(11, u20); RED(12, u21); RED(13, u22);
    RED(14, u30); RED(15, u31); RED(16, u32);
    RED(17, q00); RED(18, q01); RED(19, q02);
    RED(20, q10); RED(21, q11); RED(22, q12);
    RED(23, q20); RED(24, q21); RED(25, q22);
    RED(26, q30); RED(27, q31); RED(28, q32);
    __syncthreads();
    if (tx < 29) {
        float v = sh[0][tx] + sh[1][tx] + sh[2][tx] + sh[3][tx];
        atomicAdd(&ws[(size_t)b * WS_STRIDE + tx], (double)v);
    }
}

#define PARAMK(K_, mu0_, mu1_, mu2_, h0_, h1_, h2_, C_) {                     \
    double S0_ = w[1 + (K_)];                                                 \
    double den_ = S0_ + 1e-10;                                                \
    double Cd_ = 1.0;                                                         \
    double S1_, S2_, muv_, var_;                                              \
    S1_ = w[5 + (K_)*3 + 0]; S2_ = w[17 + (K_)*3 + 0];                        \
    muv_ = S1_ / den_;                                                        \
    var_ = (S2_ - 2.0 * muv_ * S1_ + muv_ * muv_ * S0_) / den_ + 1e-10;       \
    mu0_ = (float)muv_; h0_ = (float)(0.5 / var_);                            \
    Cd_ *= 1.0 / sqrt(6.283185307179586 * var_);                              \
    S1_ = w[5 + (K_)*3 + 1]; S2_ = w[17 + (K_)*3 + 1];                        \
    muv_ = S1_ / den_;                                                        \
    var_ = (S2_ - 2.0 * muv_ * S1_ + muv_ * muv_ * S0_) / den_ + 1e-10;       \
    mu1_ = (float)muv_; h1_ = (float)(0.5 / var_);                            \
    Cd_ *= 1.0 / sqrt(6.283185307179586 * var_);                              \
    S1_ = w[5 + (K_)*3 + 2]; S2_ = w[17 + (K_)*3 + 2];                        \
    muv_ = S1_ / den_;                                                        \
    var_ = (S2_ - 2.0 * muv_ * S1_ + muv_ * muv_ * S0_) / den_ + 1e-10;       \
    mu2_ = (float)muv_; h2_ = (float)(0.5 / var_);                            \
    Cd_ *= 1.0 / sqrt(6.283185307179586 * var_);                              \
    C_ = (float)Cd_;                                                          \
}

#define PIX2(h_, e0_, e1_, e2_, p0_, p1_, p2_, p3_) do {                      \
    float m_ = ((h_) == 1) ? 1.f : 0.f;                                       \
    float d0_, d1_, d2_, ex_, pc_;                                            \
    float mix_;                                                               \
    d0_ = (e0_) - mu00; d1_ = (e1_) - mu01; d2_ = (e2_) - mu02;               \
    ex_ = fmaf(d0_ * d0_, hv00, fmaf(d1_ * d1_, hv01, d2_ * d2_ * hv02));     \
    pc_ = (p0_) * (p0_) * (p0_);                                              \
    mix_ = C0 * pc_ * __expf(-ex_);                                           \
    d0_ = (e0_) - mu10; d1_ = (e1_) - mu11; d2_ = (e2_) - mu12;               \
    ex_ = fmaf(d0_ * d0_, hv10, fmaf(d1_ * d1_, hv11, d2_ * d2_ * hv12));     \
    pc_ = (p1_) * (p1_) * (p1_);                                              \
    mix_ = fmaf(C1 * pc_, __expf(-ex_), mix_);                                \
    d0_ = (e0_) - mu20; d1_ = (e1_) - mu21; d2_ = (e2_) - mu22;               \
    ex_ = fmaf(d0_ * d0_, hv20, fmaf(d1_ * d1_, hv21, d2_ * d2_ * hv22));     \
    pc_ = (p2_) * (p2_) * (p2_);                                              \
    mix_ = fmaf(C2 * pc_, __expf(-ex_), mix_);                                \
    d0_ = (e0_) - mu30; d1_ = (e1_) - mu31; d2_ = (e2_) - mu32;               \
    ex_ = fmaf(d0_ * d0_, hv30, fmaf(d1_ * d1_, hv31, d2_ * d2_ * hv32));     \
    pc_ = (p3_) * (p3_) * (p3_);                                              \
    mix_ = fmaf(C3 * pc_, __expf(-ex_), mix_);                                \
    lacc += m_ * __logf(mix_ + 1e-10f);                                       \
} while (0)

__global__ __launch_bounds__(256) void pass2_loglik(
        const float* __restrict__ predictions,
        const float* __restrict__ inputs,
        const int*   __restrict__ heart,
        double*      __restrict__ ws) {
    const int b = blockIdx.y;
    const double* w = ws + (size_t)b * WS_STRIDE;

    float mu00, mu01, mu02, mu10, mu11, mu12, mu20, mu21, mu22, mu30, mu31, mu32;
    float hv00, hv01, hv02, hv10, hv11, hv12, hv20, hv21, hv22, hv30, hv31, hv32;
    float C0, C1, C2, C3;
    PARAMK(0, mu00, mu01, mu02, hv00, hv01, hv02, C0);
    PARAMK(1, mu10, mu11, mu12, hv10, hv11, hv12, C1);
    PARAMK(2, mu20, mu21, mu22, hv20, hv21, hv22, C2);
    PARAMK(3, mu30, mu31, mu32, hv30, hv31, hv32, C3);

    __shared__ float4 tileBuf[8][TILE_V];      // 32 KB
    __shared__ const float4* cb[8];
    __shared__ float sh[4];

    const int tx   = threadIdx.x;
    const int lane = tx & 63;
    const int wav  = tx >> 6;

    if (tx < 8) {
        const float* p;
        if (tx == 0)      p = (const float*)(heart + (size_t)b * XY);
        else if (tx <= 3) p = inputs + (size_t)b * 3 * XY + (size_t)(tx - 1) * XY;
        else              p = predictions + (size_t)b * 5 * XY + (size_t)(tx - 3) * XY;
        cb[tx] = reinterpret_cast<const float4*>(p);
    }
    __syncthreads();

    float lacc = 0.f;
    const int tile0 = blockIdx.x * TPB;
    for (int t = 0; t < TPB; ++t) {
        STAGE_TILE(tile0 + t);
        __syncthreads();
        int4   h  = ((const int4*)tileBuf[0])[tx];
        float4 f0 = tileBuf[1][tx], f1 = tileBuf[2][tx], f2 = tileBuf[3][tx];
        float4 g0 = tileBuf[4][tx], g1 = tileBuf[5][tx], g2 = tileBuf[6][tx], g3 = tileBuf[7][tx];
        PIX2(h.x, f0.x, f1.x, f2.x, g0.x, g1.x, g2.x, g3.x);
        PIX2(h.y, f0.y, f1.y, f2.y, g0.y, g1.y, g2.y, g3.y);
        PIX2(h.z, f0.z, f1.z, f2.z, g0.z, g1.z, g2.z, g3.z);
        PIX2(h.w, f0.w, f1.w, f2.w, g0.w, g1.w, g2.w, g3.w);
        __syncthreads();
    }

    float v = waveReduce64(lacc);
    if (lane == 0) sh[wav] = v;
    __syncthreads();
    if (tx == 0) {
        float tsum = sh[0] + sh[1] + sh[2] + sh[3];
        atomicAdd(&ws[(size_t)b * WS_STRIDE + 29], (double)tsum);
    }
}

__global__ void finalize_kernel(const double* __restrict__ ws, float* __restrict__ out) {
    const int lane = threadIdx.x;
    double v = 0.0;
    if (lane < NB) {
        double cntv = ws[(size_t)lane * WS_STRIDE + 0];
        double ll   = ws[(size_t)lane * WS_STRIDE + 29];
        v = -ll / cntv;
    }
#pragma unroll
    for (int off = 8; off > 0; off >>= 1) v += __shfl_down(v, off, 64);
    if (lane == 0) out[0] = (float)(v / (double)NB);
}

extern "C" void kernel_launch(void* const* d_in, const int* in_sizes, int n_in,
                              void* d_out, int out_size, void* d_ws, size_t ws_size,
                              hipStream_t stream) {
    const float* predictions = (const float*)d_in[0];
    const float* inputs      = (const float*)d_in[1];
    const int*   heart       = (const int*)d_in[2];
    float*  out = (float*)d_out;
    double* ws  = (double*)d_ws;

    // zero the accumulator workspace (harness poisons it with 0xAA)
    hipMemsetAsync(d_ws, 0, (size_t)NB * WS_STRIDE * sizeof(double), stream);

    pass1_moments<<<dim3(GRIDX, NB), BLK, 0, stream>>>(predictions, inputs, heart, ws);
    pass2_loglik <<<dim3(GRIDX, NB), BLK, 0, stream>>>(predictions, inputs, heart, ws);
    finalize_kernel<<<1, 64, 0, stream>>>(ws, out);
}